// Round 3
// baseline (224.808 us; speedup 1.0000x reference)
//
#include <hip/hip_runtime.h>
#include <hip/hip_bf16.h>

#define B_   4
#define H_   16
#define SEQ  2048
#define DH   64
#define BM   128
#define BN   64
#define NBH  (B_ * H_)
#define NELEM (NBH * SEQ * DH)   // 8388608 elements per tensor

typedef __bf16 bf16x8 __attribute__((ext_vector_type(8)));
typedef float  f32x4  __attribute__((ext_vector_type(4)));
typedef unsigned short u16x8 __attribute__((ext_vector_type(8)));
typedef unsigned short u16x4 __attribute__((ext_vector_type(4)));

__device__ __forceinline__ unsigned short f2bu(float x) {
    __hip_bfloat16 h = __float2bfloat16(x);
    return __builtin_bit_cast(unsigned short, h);
}

__device__ __forceinline__ void ld_lds16(const unsigned short* g, unsigned short* l) {
    __builtin_amdgcn_global_load_lds(
        (const __attribute__((address_space(1))) unsigned int*)(g),
        (__attribute__((address_space(3))) unsigned int*)(l), 16, 0, 0);
}

// ---------- fused prepass: K fp32->bf16 (same layout) + V fp32->bf16 transposed ----------
__global__ __launch_bounds__(256)
void prep_kv(const float* __restrict__ K, const float* __restrict__ V,
             unsigned short* __restrict__ Kb, unsigned short* __restrict__ Vt) {
    __shared__ unsigned short tile[64 * 72];
    const int bh = blockIdx.y;
    const int s0 = blockIdx.x * 64;
    const int t  = threadIdx.x;

    { // K convert: 64 rows x 64 cols contiguous, 16B stores
        const float* Ki = K + (size_t)bh * SEQ * DH + (size_t)s0 * DH;
        unsigned short* Ko = Kb + (size_t)bh * SEQ * DH + (size_t)s0 * DH;
        for (int jj = 0; jj < 2; ++jj) {
            const int e = (jj * 256 + t) * 8;
            const float4 a = *reinterpret_cast<const float4*>(Ki + e);
            const float4 b = *reinterpret_cast<const float4*>(Ki + e + 4);
            u16x8 u;
            u[0] = f2bu(a.x); u[1] = f2bu(a.y); u[2] = f2bu(a.z); u[3] = f2bu(a.w);
            u[4] = f2bu(b.x); u[5] = f2bu(b.y); u[6] = f2bu(b.z); u[7] = f2bu(b.w);
            *reinterpret_cast<u16x8*>(Ko + e) = u;
        }
    }

    const float* Vb = V + (size_t)bh * SEQ * DH + (size_t)s0 * DH;
    unsigned short* Vo = Vt + (size_t)bh * DH * SEQ;
    {
        const int sl = t >> 2, d0 = (t & 3) * 16;
        for (int c = 0; c < 4; ++c) {
            const float4 v = *reinterpret_cast<const float4*>(Vb + sl * DH + d0 + c * 4);
            u16x4 u; u[0] = f2bu(v.x); u[1] = f2bu(v.y); u[2] = f2bu(v.z); u[3] = f2bu(v.w);
            *reinterpret_cast<u16x4*>(&tile[sl * 72 + d0 + c * 4]) = u;
        }
    }
    __syncthreads();
    { // transposed store: each lane 2x16B contiguous; 4-lane quad covers a full
      // 128B d-row cache line
        const int d = t >> 2, sc0 = (t & 3) * 16;
        for (int c = 0; c < 2; ++c) {
            const int s = sc0 + c * 8;
            u16x8 u;
#pragma unroll
            for (int r = 0; r < 8; ++r) u[r] = tile[(s + r) * 72 + d];
            *reinterpret_cast<u16x8*>(Vo + (size_t)d * SEQ + s0 + s) = u;
        }
    }
}

// ---------- main flash-attention kernel ----------
// R8: break the inter-wave convoy (R7 lesson: pipes ran sequentially; extra
// waves didn't overlap them) with an INTRA-WAVE 4-stage pipeline per KV tile:
//   P0: V-frag prefetch ks=0 + QK kv[0:32)   (8 MFMA, LDS streams)
//   P1: QK kv[32:64) (8 MFMA on fresh ds_reads) || softmax half 0 (VALU)
//   P2: V-frag prefetch ks=1 + softmax half 1 || PV half 0 (8 MFMA, reg ops)
//   P3: PV half 1 (8 MFMA from regs)
// Requires pair-adjacent softmax halves -> new alpha:
//   grow(s) = 32*(s>>5) + 8*((s>>2)&3) + 4*((s>>4)&1) + (s&3)
// (derivation: exp2(Sacc[nt][r]) = P[q][32*(nt>>1)+8*quad+4*(nt&1)+r], so with
//  nt = 2ks+m the packed element j = 4m+r matches V's k-index ks*32+quad*8+j.)
// LDS read addresses: nt/dt components folded to compile-time offset:
// immediates; only 4 runtime addr VGPRs (krd0/krd1/vrd0/vrd1).
__global__ __launch_bounds__(256, 4)
void fa_fwd(const float* __restrict__ Qg, const unsigned short* __restrict__ Kb,
            const unsigned short* __restrict__ Vtb, float* __restrict__ Og)
{
    __shared__ __attribute__((aligned(16))) unsigned short smem[16384]; // 32 KB, 2 bufs

    const int tid  = threadIdx.x;
    const int lane = tid & 63;
    const int wave = tid >> 6;
    const int l15  = lane & 15;
    const int quad = lane >> 4;

    // XCD-bijective swizzle: xcd = bid&7 gets bh in [8*xcd, 8*xcd+8), qtile fastest
    const int bid   = blockIdx.x;          // 0..1023
    const int xcd   = bid & 7;
    const int jj    = bid >> 3;            // 0..127
    const int bh    = (xcd << 3) | (jj >> 4);
    const int qtile = jj & 15;

    const float*          Qb  = Qg  + (size_t)bh * SEQ * DH;
    const unsigned short* Kbh = Kb  + (size_t)bh * SEQ * DH;
    const unsigned short* Vbh = Vtb + (size_t)bh * DH * SEQ;
    float*                Ob  = Og  + (size_t)bh * SEQ * DH;

    const int qrow0 = qtile * BM + wave * 32;

    const float CS = 0.125f * 1.4426950408889634f; // folded into Qf

    // Q fragments (B-operand layout: n=l15, k=quad*8+j), PRE-SCALED by CS
    bf16x8 Qf[2][2];
    for (int rt = 0; rt < 2; ++rt) {
        const float* qsrc = Qb + (size_t)(qrow0 + rt * 16 + l15) * DH + quad * 8;
        for (int kt = 0; kt < 2; ++kt) {
            const float4 a = *reinterpret_cast<const float4*>(qsrc + kt * 32);
            const float4 b = *reinterpret_cast<const float4*>(qsrc + kt * 32 + 4);
            union { bf16x8 v; unsigned short u[8]; } tmp;
            tmp.u[0] = f2bu(a.x * CS); tmp.u[1] = f2bu(a.y * CS);
            tmp.u[2] = f2bu(a.z * CS); tmp.u[3] = f2bu(a.w * CS);
            tmp.u[4] = f2bu(b.x * CS); tmp.u[5] = f2bu(b.y * CS);
            tmp.u[6] = f2bu(b.z * CS); tmp.u[7] = f2bu(b.w * CS);
            Qf[rt][kt] = tmp.v;
        }
    }

    // splat-1.0 bf16 for row-sum MFMA
    bf16x8 ones;
    {
        union { bf16x8 v; unsigned short u[8]; } t;
        for (int i = 0; i < 8; ++i) t.u[i] = 0x3F80;
        ones = t.v;
    }
    const f32x4 fzero = {0.f, 0.f, 0.f, 0.f};

    f32x4 Oacc[2][4];
    f32x4 Lacc[2];
    for (int rt = 0; rt < 2; ++rt) {
        Lacc[rt] = fzero;
        for (int dt = 0; dt < 4; ++dt) Oacc[rt][dt] = fzero;
    }

    // staging: global source pointers (bumped per tile) + LDS dest offsets
    const unsigned short* kp[2];
    const unsigned short* vp[2];
    int koff_st[2], voff_st[2];
    for (int i = 0; i < 2; ++i) {
        const int beta = i * 256 + tid;
        { // K: pair-adjacent alpha row, swizzled col block (8 blocks of 8 shorts)
            const int s    = beta >> 3;            // LDS row 0..63
            const int b    = beta & 7;
            const int gnat = b ^ (s & 7);
            const int grow = 32 * (s >> 5) + 8 * ((s >> 2) & 3)
                           + 4 * ((s >> 4) & 1) + (s & 3);   // alpha64' (pair-adjacent)
            kp[i]  = Kbh + (size_t)grow * DH + gnat * 8;
        }
        { // V: natural d-row, swizzled col block (8 blocks of 8 shorts)
            const int d = beta >> 3;               // 0..63
            const int g = (beta & 7) ^ (d & 7);
            vp[i]  = Vbh + (size_t)d * SEQ + g * 8;
        }
        koff_st[i] = (i * 256 + wave * 64) * 8;           // wave-uniform
        voff_st[i] = 4096 + (i * 256 + wave * 64) * 8;    // wave-uniform
    }

    // runtime address components (nt/dt parts folded into offset: immediates)
    const int sx   = l15 & 7;
    const int krd0 = l15 * 64 + ((quad    ) ^ sx) * 8;
    const int krd1 = l15 * 64 + ((quad + 4) ^ sx) * 8;
    const int vrd0 = l15 * 64 + ((quad    ) ^ sx) * 8;   // ks=0: block (0*4+quad)^sx
    const int vrd1 = l15 * 64 + ((quad + 4) ^ sx) * 8;   // ks=1: block (1*4+quad)^sx

#define STAGE(BUF) do {                                                        \
        _Pragma("unroll")                                                      \
        for (int i = 0; i < 2; ++i) {                                          \
            ld_lds16(kp[i], smem + (BUF) * 8192 + koff_st[i]);                 \
            kp[i] += BN * DH;                                                  \
        }                                                                      \
        _Pragma("unroll")                                                      \
        for (int i = 0; i < 2; ++i) {                                          \
            ld_lds16(vp[i], smem + (BUF) * 8192 + voff_st[i]);                 \
            vp[i] += BN;                                                       \
        }                                                                      \
    } while (0)

#define QK_PAIR(BUF, NT0, SACC) do {                                           \
        _Pragma("unroll")                                                      \
        for (int m = 0; m < 2; ++m) {                                          \
            const bf16x8 kf0 = *reinterpret_cast<const bf16x8*>(               \
                &smem[(BUF) * 8192 + ((NT0) + m) * 1024 + krd0]);              \
            const bf16x8 kf1 = *reinterpret_cast<const bf16x8*>(               \
                &smem[(BUF) * 8192 + ((NT0) + m) * 1024 + krd1]);              \
            SACC[0][m] = __builtin_amdgcn_mfma_f32_16x16x32_bf16(kf0, Qf[0][0], fzero,       0, 0, 0); \
            SACC[0][m] = __builtin_amdgcn_mfma_f32_16x16x32_bf16(kf1, Qf[0][1], SACC[0][m], 0, 0, 0); \
            SACC[1][m] = __builtin_amdgcn_mfma_f32_16x16x32_bf16(kf0, Qf[1][0], fzero,       0, 0, 0); \
            SACC[1][m] = __builtin_amdgcn_mfma_f32_16x16x32_bf16(kf1, Qf[1][1], SACC[1][m], 0, 0, 0); \
        }                                                                      \
    } while (0)

#define LOAD_BFR(BUF, DST, VRD) do {                                           \
        _Pragma("unroll")                                                      \
        for (int dt = 0; dt < 4; ++dt)                                         \
            DST[dt] = *reinterpret_cast<const bf16x8*>(                        \
                &smem[(BUF) * 8192 + 4096 + dt * 1024 + (VRD)]);               \
    } while (0)

#define SM_HALF(SACC, KS) do {                                                 \
        _Pragma("unroll")                                                      \
        for (int rt = 0; rt < 2; ++rt) {                                       \
            union { bf16x8 v; unsigned w[4]; } a;                              \
            _Pragma("unroll")                                                  \
            for (int m = 0; m < 2; ++m) {                                      \
                _Pragma("unroll")                                              \
                for (int rp = 0; rp < 2; ++rp) {                               \
                    const float p0 = __builtin_amdgcn_exp2f(SACC[rt][m][2 * rp    ]); \
                    const float p1 = __builtin_amdgcn_exp2f(SACC[rt][m][2 * rp + 1]); \
                    const unsigned u0 = __builtin_bit_cast(unsigned, p0) + 0x8000u; \
                    const unsigned u1 = __builtin_bit_cast(unsigned, p1) + 0x8000u; \
                    a.w[m * 2 + rp] = __builtin_amdgcn_perm(u1, u0, 0x07060302u); \
                }                                                              \
            }                                                                  \
            af[rt][KS] = a.v;                                                  \
            Lacc[rt] = __builtin_amdgcn_mfma_f32_16x16x32_bf16(a.v, ones, Lacc[rt], 0, 0, 0); \
        }                                                                      \
    } while (0)

#define PV_HALF(KS, BFR) do {                                                  \
        _Pragma("unroll")                                                      \
        for (int dt = 0; dt < 4; ++dt) {                                       \
            Oacc[0][dt] = __builtin_amdgcn_mfma_f32_16x16x32_bf16(af[0][KS], BFR[dt], Oacc[0][dt], 0, 0, 0); \
            Oacc[1][dt] = __builtin_amdgcn_mfma_f32_16x16x32_bf16(af[1][KS], BFR[dt], Oacc[1][dt], 0, 0, 0); \
        }                                                                      \
    } while (0)

#define COMPUTE(BUF) do {                                                      \
        f32x4 SA[2][2], SB[2][2];                                              \
        bf16x8 bfr0[4], bfr1[4];                                               \
        bf16x8 af[2][2];                                                       \
        /* P0: V ks=0 prefetch + QK kv[0:32) */                                \
        LOAD_BFR(BUF, bfr0, vrd0);                                             \
        __builtin_amdgcn_s_setprio(1);                                         \
        QK_PAIR(BUF, 0, SA);                                                   \
        __builtin_amdgcn_s_setprio(0);                                         \
        /* P1: QK kv[32:64) || softmax half 0 */                               \
        QK_PAIR(BUF, 2, SB);                                                   \
        SM_HALF(SA, 0);                                                        \
        /* P2: V ks=1 prefetch + softmax half 1 || PV half 0 */                \
        LOAD_BFR(BUF, bfr1, vrd1);                                             \
        SM_HALF(SB, 1);                                                        \
        PV_HALF(0, bfr0);                                                      \
        /* P3: PV half 1 (all-register) */                                     \
        __builtin_amdgcn_s_setprio(1);                                         \
        PV_HALF(1, bfr1);                                                      \
        __builtin_amdgcn_s_setprio(0);                                         \
    } while (0)

    // ---- 2-phase main loop over 32 KV tiles: stage(next); compute(cur); barrier ----
    STAGE(0);                 // tile 0 -> buf0
    __syncthreads();

#pragma unroll 1
    for (int it2 = 0; it2 < 15; ++it2) {
        STAGE(1);             // tile 2*it2+1 -> buf1 (in flight during compute)
        COMPUTE(0);           // tile 2*it2
        __syncthreads();
        STAGE(0);             // tile 2*it2+2 -> buf0
        COMPUTE(1);           // tile 2*it2+1
        __syncthreads();
    }
    STAGE(1);                 // tile 31 -> buf1
    COMPUTE(0);               // tile 30
    __syncthreads();
    COMPUTE(1);               // tile 31

#undef STAGE
#undef QK_PAIR
#undef LOAD_BFR
#undef SM_HALF
#undef PV_HALF
#undef COMPUTE

    // ---- epilogue: Lacc rows already aligned with Oacc rows; no shuffles ----
    for (int rt = 0; rt < 2; ++rt) {
        for (int r = 0; r < 4; ++r) {
            const float inv = 1.0f / Lacc[rt][r];
            const int row = qrow0 + rt * 16 + quad * 4 + r;
            float* orow = Ob + (size_t)row * DH + l15;
            for (int dt = 0; dt < 4; ++dt)
                orow[dt * 16] = Oacc[rt][dt][r] * inv;
        }
    }
}

extern "C" void kernel_launch(void* const* d_in, const int* in_sizes, int n_in,
                              void* d_out, int out_size, void* d_ws, size_t ws_size,
                              hipStream_t stream) {
    const float* Q = (const float*)d_in[0];
    const float* K = (const float*)d_in[1];
    const float* V = (const float*)d_in[2];
    float* O = (float*)d_out;

    unsigned short* Kb = (unsigned short*)d_ws;   // 16 MB bf16 K
    unsigned short* Vt = Kb + (size_t)NELEM;      // 16 MB bf16 V^T

    prep_kv<<<dim3(SEQ / 64, NBH), 256, 0, stream>>>(K, V, Kb, Vt);
    fa_fwd<<<dim3((SEQ / BM) * NBH), dim3(256), 0, stream>>>(Q, Kb, Vt, O);
}

// Round 4
// 199.256 us; speedup vs baseline: 1.1282x; 1.1282x over previous
//
#include <hip/hip_runtime.h>
#include <hip/hip_bf16.h>

#define B_   4
#define H_   16
#define SEQ  2048
#define DH   64
#define BM   256
#define BN   64
#define NBH  (B_ * H_)
#define NELEM (NBH * SEQ * DH)   // 8388608 elements per tensor

typedef __bf16 bf16x8 __attribute__((ext_vector_type(8)));
typedef float  f32x4  __attribute__((ext_vector_type(4)));
typedef unsigned short u16x8 __attribute__((ext_vector_type(8)));
typedef unsigned short u16x4 __attribute__((ext_vector_type(4)));

__device__ __forceinline__ unsigned short f2bu(float x) {
    __hip_bfloat16 h = __float2bfloat16(x);
    return __builtin_bit_cast(unsigned short, h);
}

__device__ __forceinline__ void ld_lds16(const unsigned short* g, unsigned short* l) {
    __builtin_amdgcn_global_load_lds(
        (const __attribute__((address_space(1))) unsigned int*)(g),
        (__attribute__((address_space(3))) unsigned int*)(l), 16, 0, 0);
}

// ---------- fused prepass: K fp32->bf16 (same layout) + V fp32->bf16 transposed ----------
__global__ __launch_bounds__(256)
void prep_kv(const float* __restrict__ K, const float* __restrict__ V,
             unsigned short* __restrict__ Kb, unsigned short* __restrict__ Vt) {
    __shared__ unsigned short tile[64 * 72];
    const int bh = blockIdx.y;
    const int s0 = blockIdx.x * 64;
    const int t  = threadIdx.x;

    { // K convert: 64 rows x 64 cols contiguous, 16B stores
        const float* Ki = K + (size_t)bh * SEQ * DH + (size_t)s0 * DH;
        unsigned short* Ko = Kb + (size_t)bh * SEQ * DH + (size_t)s0 * DH;
        for (int jj = 0; jj < 2; ++jj) {
            const int e = (jj * 256 + t) * 8;
            const float4 a = *reinterpret_cast<const float4*>(Ki + e);
            const float4 b = *reinterpret_cast<const float4*>(Ki + e + 4);
            u16x8 u;
            u[0] = f2bu(a.x); u[1] = f2bu(a.y); u[2] = f2bu(a.z); u[3] = f2bu(a.w);
            u[4] = f2bu(b.x); u[5] = f2bu(b.y); u[6] = f2bu(b.z); u[7] = f2bu(b.w);
            *reinterpret_cast<u16x8*>(Ko + e) = u;
        }
    }

    const float* Vb = V + (size_t)bh * SEQ * DH + (size_t)s0 * DH;
    unsigned short* Vo = Vt + (size_t)bh * DH * SEQ;
    {
        const int sl = t >> 2, d0 = (t & 3) * 16;
        for (int c = 0; c < 4; ++c) {
            const float4 v = *reinterpret_cast<const float4*>(Vb + sl * DH + d0 + c * 4);
            u16x4 u; u[0] = f2bu(v.x); u[1] = f2bu(v.y); u[2] = f2bu(v.z); u[3] = f2bu(v.w);
            *reinterpret_cast<u16x4*>(&tile[sl * 72 + d0 + c * 4]) = u;
        }
    }
    __syncthreads();
    { // transposed store: each lane 2x16B contiguous
        const int d = t >> 2, sc0 = (t & 3) * 16;
        for (int c = 0; c < 2; ++c) {
            const int s = sc0 + c * 8;
            u16x8 u;
#pragma unroll
            for (int r = 0; r < 8; ++r) u[r] = tile[(s + r) * 72 + d];
            *reinterpret_cast<u16x8*>(Vo + (size_t)d * SEQ + s0 + s) = u;
        }
    }
}

// ---------- main flash-attention kernel ----------
// R9: LDS-read amortization. R7/R8 post-mortem: per-CU pipe budget was
// LDS-read ~41us > matrix ~36us > VALU-only ~25us; R8's reg-prefetch fix
// spilled (WRITE_SIZE 32->92MB). Instead: 64 q-rows per wave (BM=256, 4
// waves, grid 512 = 2 blocks/CU) so each K/V LDS fragment read feeds 4
// MFMAs (rt=0..3) instead of 2 -> LDS reads per unit work HALVED
// (~21us/CU), matrix (~37us) becomes the dominant pipe.
//  - launch_bounds(256,2): VGPR cap 256 for ~210 live (Oacc 64 + Qf 32 +
//    Sacc 32 + af 32 + Lacc 16 + addr/ptr). NO spill headroom issue.
//  - Sacc live range capped at 32 regs: QK nt={0,1} -> pack ks=0 ->
//    QK nt={2,3} -> pack ks=1 (VALU pack overlaps second QK MFMA cluster).
//  - staging / alpha' (pair-adjacent) / XOR swizzles byte-identical to the
//    HW-verified R8 versions; only rt extent changed.
//  - XCD-bijective swizzle for 512 blocks: xcd=bid&7 owns bh [8x,8x+8).
__global__ __launch_bounds__(256, 2)
void fa_fwd(const float* __restrict__ Qg, const unsigned short* __restrict__ Kb,
            const unsigned short* __restrict__ Vtb, float* __restrict__ Og)
{
    __shared__ __attribute__((aligned(16))) unsigned short smem[16384]; // 32 KB, 2 bufs

    const int tid  = threadIdx.x;
    const int lane = tid & 63;
    const int wave = tid >> 6;
    const int l15  = lane & 15;
    const int quad = lane >> 4;

    // XCD-bijective swizzle: 512 blocks, 64 per XCD, bh-major within XCD
    const int bid   = blockIdx.x;          // 0..511
    const int xcd   = bid & 7;
    const int jj    = bid >> 3;            // 0..63
    const int bh    = (xcd << 3) | (jj >> 3);
    const int qtile = jj & 7;

    const float*          Qb  = Qg  + (size_t)bh * SEQ * DH;
    const unsigned short* Kbh = Kb  + (size_t)bh * SEQ * DH;
    const unsigned short* Vbh = Vtb + (size_t)bh * DH * SEQ;
    float*                Ob  = Og  + (size_t)bh * SEQ * DH;

    const int qrow0 = qtile * BM + wave * 64;

    const float CS = 0.125f * 1.4426950408889634f; // folded into Qf

    // Q fragments (B-operand layout: n=l15, k=quad*8+j), PRE-SCALED by CS
    bf16x8 Qf[4][2];
#pragma unroll
    for (int rt = 0; rt < 4; ++rt) {
        const float* qsrc = Qb + (size_t)(qrow0 + rt * 16 + l15) * DH + quad * 8;
#pragma unroll
        for (int kt = 0; kt < 2; ++kt) {
            const float4 a = *reinterpret_cast<const float4*>(qsrc + kt * 32);
            const float4 b = *reinterpret_cast<const float4*>(qsrc + kt * 32 + 4);
            union { bf16x8 v; unsigned short u[8]; } tmp;
            tmp.u[0] = f2bu(a.x * CS); tmp.u[1] = f2bu(a.y * CS);
            tmp.u[2] = f2bu(a.z * CS); tmp.u[3] = f2bu(a.w * CS);
            tmp.u[4] = f2bu(b.x * CS); tmp.u[5] = f2bu(b.y * CS);
            tmp.u[6] = f2bu(b.z * CS); tmp.u[7] = f2bu(b.w * CS);
            Qf[rt][kt] = tmp.v;
        }
    }

    // splat-1.0 bf16 for row-sum MFMA
    bf16x8 ones;
    {
        union { bf16x8 v; unsigned short u[8]; } t;
        for (int i = 0; i < 8; ++i) t.u[i] = 0x3F80;
        ones = t.v;
    }
    const f32x4 fzero = {0.f, 0.f, 0.f, 0.f};

    f32x4 Oacc[4][4];
    f32x4 Lacc[4];
#pragma unroll
    for (int rt = 0; rt < 4; ++rt) {
        Lacc[rt] = fzero;
#pragma unroll
        for (int dt = 0; dt < 4; ++dt) Oacc[rt][dt] = fzero;
    }

    // staging: global source pointers (bumped per tile) + LDS dest offsets
    const unsigned short* kp[2];
    const unsigned short* vp[2];
    int koff_st[2], voff_st[2];
    for (int i = 0; i < 2; ++i) {
        const int beta = i * 256 + tid;
        { // K: pair-adjacent alpha row, swizzled col block (8 blocks of 8 shorts)
            const int s    = beta >> 3;            // LDS row 0..63
            const int b    = beta & 7;
            const int gnat = b ^ (s & 7);
            const int grow = 32 * (s >> 5) + 8 * ((s >> 2) & 3)
                           + 4 * ((s >> 4) & 1) + (s & 3);   // alpha64' (pair-adjacent)
            kp[i]  = Kbh + (size_t)grow * DH + gnat * 8;
        }
        { // V: natural d-row, swizzled col block (8 blocks of 8 shorts)
            const int d = beta >> 3;               // 0..63
            const int g = (beta & 7) ^ (d & 7);
            vp[i]  = Vbh + (size_t)d * SEQ + g * 8;
        }
        koff_st[i] = (i * 256 + wave * 64) * 8;           // wave-uniform
        voff_st[i] = 4096 + (i * 256 + wave * 64) * 8;    // wave-uniform
    }

    // runtime address components (nt/dt parts folded into offset: immediates)
    const int sx   = l15 & 7;
    const int krd0 = l15 * 64 + ((quad    ) ^ sx) * 8;
    const int krd1 = l15 * 64 + ((quad + 4) ^ sx) * 8;
    const int vrd0 = l15 * 64 + ((quad    ) ^ sx) * 8;   // ks=0: block (0*4+quad)^sx
    const int vrd1 = l15 * 64 + ((quad + 4) ^ sx) * 8;   // ks=1: block (1*4+quad)^sx

#define STAGE(BUF) do {                                                        \
        _Pragma("unroll")                                                      \
        for (int i = 0; i < 2; ++i) {                                          \
            ld_lds16(kp[i], smem + (BUF) * 8192 + koff_st[i]);                 \
            kp[i] += BN * DH;                                                  \
        }                                                                      \
        _Pragma("unroll")                                                      \
        for (int i = 0; i < 2; ++i) {                                          \
            ld_lds16(vp[i], smem + (BUF) * 8192 + voff_st[i]);                 \
            vp[i] += BN;                                                       \
        }                                                                      \
    } while (0)

// QK for kv pair {NT0, NT0+1}: 2x2 K-fragment reads, each feeding 4 rt MFMAs
#define QK_PAIR(BUF, NT0, SACC) do {                                           \
        _Pragma("unroll")                                                      \
        for (int m = 0; m < 2; ++m) {                                          \
            const bf16x8 kf0 = *reinterpret_cast<const bf16x8*>(               \
                &smem[(BUF) * 8192 + ((NT0) + m) * 1024 + krd0]);              \
            const bf16x8 kf1 = *reinterpret_cast<const bf16x8*>(               \
                &smem[(BUF) * 8192 + ((NT0) + m) * 1024 + krd1]);              \
            _Pragma("unroll")                                                  \
            for (int rt = 0; rt < 4; ++rt) {                                   \
                SACC[rt][m] = __builtin_amdgcn_mfma_f32_16x16x32_bf16(kf0, Qf[rt][0], fzero,       0, 0, 0); \
                SACC[rt][m] = __builtin_amdgcn_mfma_f32_16x16x32_bf16(kf1, Qf[rt][1], SACC[rt][m], 0, 0, 0); \
            }                                                                  \
        }                                                                      \
    } while (0)

// exp2 + bf16 pack of one kv-32 half into af[*][KS] + L row-sum MFMA
#define SM_HALF(SACC, KS) do {                                                 \
        _Pragma("unroll")                                                      \
        for (int rt = 0; rt < 4; ++rt) {                                       \
            union { bf16x8 v; unsigned w[4]; } a;                              \
            _Pragma("unroll")                                                  \
            for (int m = 0; m < 2; ++m) {                                      \
                _Pragma("unroll")                                              \
                for (int rp = 0; rp < 2; ++rp) {                               \
                    const float p0 = __builtin_amdgcn_exp2f(SACC[rt][m][2 * rp    ]); \
                    const float p1 = __builtin_amdgcn_exp2f(SACC[rt][m][2 * rp + 1]); \
                    const unsigned u0 = __builtin_bit_cast(unsigned, p0) + 0x8000u; \
                    const unsigned u1 = __builtin_bit_cast(unsigned, p1) + 0x8000u; \
                    a.w[m * 2 + rp] = __builtin_amdgcn_perm(u1, u0, 0x07060302u); \
                }                                                              \
            }                                                                  \
            af[rt][KS] = a.v;                                                  \
            Lacc[rt] = __builtin_amdgcn_mfma_f32_16x16x32_bf16(a.v, ones, Lacc[rt], 0, 0, 0); \
        }                                                                      \
    } while (0)

// PV for one kv-32 half: 4 V-fragment reads, each feeding 4 rt MFMAs
#define PV_HALF(BUF, KS, VRD) do {                                             \
        _Pragma("unroll")                                                      \
        for (int dt = 0; dt < 4; ++dt) {                                       \
            const bf16x8 bfr = *reinterpret_cast<const bf16x8*>(               \
                &smem[(BUF) * 8192 + 4096 + dt * 1024 + (VRD)]);               \
            _Pragma("unroll")                                                  \
            for (int rt = 0; rt < 4; ++rt)                                     \
                Oacc[rt][dt] = __builtin_amdgcn_mfma_f32_16x16x32_bf16(af[rt][KS], bfr, Oacc[rt][dt], 0, 0, 0); \
        }                                                                      \
    } while (0)

#define COMPUTE(BUF) do {                                                      \
        f32x4 SA[4][2], SB[4][2];                                              \
        bf16x8 af[4][2];                                                       \
        __builtin_amdgcn_s_setprio(1);                                         \
        QK_PAIR(BUF, 0, SA);                                                   \
        __builtin_amdgcn_s_setprio(0);                                         \
        SM_HALF(SA, 0);            /* VALU pack overlaps next MFMA cluster */  \
        __builtin_amdgcn_s_setprio(1);                                         \
        QK_PAIR(BUF, 2, SB);                                                   \
        __builtin_amdgcn_s_setprio(0);                                         \
        SM_HALF(SB, 1);                                                        \
        __builtin_amdgcn_s_setprio(1);                                         \
        PV_HALF(BUF, 0, vrd0);                                                 \
        PV_HALF(BUF, 1, vrd1);                                                 \
        __builtin_amdgcn_s_setprio(0);                                         \
    } while (0)

    // ---- 2-phase main loop over 32 KV tiles: stage(next); compute(cur); barrier ----
    STAGE(0);                 // tile 0 -> buf0
    __syncthreads();

#pragma unroll 1
    for (int it2 = 0; it2 < 15; ++it2) {
        STAGE(1);             // tile 2*it2+1 -> buf1 (in flight during compute)
        COMPUTE(0);           // tile 2*it2
        __syncthreads();
        STAGE(0);             // tile 2*it2+2 -> buf0
        COMPUTE(1);           // tile 2*it2+1
        __syncthreads();
    }
    STAGE(1);                 // tile 31 -> buf1
    COMPUTE(0);               // tile 30
    __syncthreads();
    COMPUTE(1);               // tile 31

#undef STAGE
#undef QK_PAIR
#undef SM_HALF
#undef PV_HALF
#undef COMPUTE

    // ---- epilogue: Lacc rows already aligned with Oacc rows; no shuffles ----
#pragma unroll
    for (int rt = 0; rt < 4; ++rt) {
#pragma unroll
        for (int r = 0; r < 4; ++r) {
            const float inv = 1.0f / Lacc[rt][r];
            const int row = qrow0 + rt * 16 + quad * 4 + r;
            float* orow = Ob + (size_t)row * DH + l15;
#pragma unroll
            for (int dt = 0; dt < 4; ++dt)
                orow[dt * 16] = Oacc[rt][dt][r] * inv;
        }
    }
}

extern "C" void kernel_launch(void* const* d_in, const int* in_sizes, int n_in,
                              void* d_out, int out_size, void* d_ws, size_t ws_size,
                              hipStream_t stream) {
    const float* Q = (const float*)d_in[0];
    const float* K = (const float*)d_in[1];
    const float* V = (const float*)d_in[2];
    float* O = (float*)d_out;

    unsigned short* Kb = (unsigned short*)d_ws;   // 16 MB bf16 K
    unsigned short* Vt = Kb + (size_t)NELEM;      // 16 MB bf16 V^T

    prep_kv<<<dim3(SEQ / 64, NBH), 256, 0, stream>>>(K, V, Kb, Vt);
    fa_fwd<<<dim3((SEQ / BM) * NBH), dim3(256), 0, stream>>>(Q, Kb, Vt, O);
}